// Round 4
// baseline (315324.512 us; speedup 1.0000x reference)
//
#include <hip/hip_runtime.h>

#define BB 128      // batch
#define TT 1024     // seq len
#define II 64       // input size
#define HH 512      // hidden
#define KK 576      // II + HH
#define NBLK 256    // one block per pair of h-columns
#define NTHR 256

typedef unsigned int u32;

// Persistent LSTM. Round-3 lesson: agent-scope fences (buffer_wbl2/inv) and
// same-line RMW atomics cost ~70us/step on 8-XCD gfx950 (WRITE_SIZE 19GB of
// L2-writeback churn). This version has ZERO fences and ZERO RMWs:
//  - h exchanged via relaxed AGENT atomic 4B stores/loads (sc0/sc1 bypass,
//    coherent at IF$). hbuf transposed [j][b] so both sides coalesce.
//  - grid barrier = 256 monotonic per-block flags; writer: syncthreads
//    (drains vmcnt -> sc1 stores at coherence point) + 1 relaxed flag store;
//    reader: thread u polls flags[u], then syncthreads.
__global__ __launch_bounds__(NTHR, 1)
void lstm_persist(const float* __restrict__ x,
                  const float* __restrict__ W_ih,
                  const float* __restrict__ W_hh,
                  const float* __restrict__ b_ih,
                  const float* __restrict__ b_hh,
                  const float* __restrict__ W_fc,
                  const float* __restrict__ b_fc,
                  float* __restrict__ out,
                  float* __restrict__ hbuf,   // 2 x [HH][BB] f32 (TRANSPOSED)
                  u32*   __restrict__ flags)  // [NBLK] monotonic step counters
{
    __shared__ float Wl[8][KK];      // 18432B
    __shared__ float vx[BB][68];     // 34816B  one 64-wide K chunk, pad 68
    __shared__ float gl[8][BB];      //  4096B
    __shared__ float yl[2][BB];      //  1024B
    __shared__ float wfc[HH];        //  2048B
    __shared__ float bias[8];        //    32B  => 60448B (<64KB coop limit)

    const int u  = threadIdx.x;
    const int g  = blockIdx.x;
    const int j0 = g << 1;

    // ---- one-time weight staging ----
    for (int r = 0; r < 8; ++r) {
        const int R = (r >> 1) * HH + j0 + (r & 1);
        for (int k = u; k < KK; k += NTHR)
            Wl[r][k] = (k < II) ? W_ih[(size_t)R * II + k]
                                : W_hh[(size_t)R * HH + (k - II)];
    }
    if (u < 8) {
        const int R = (u >> 1) * HH + j0 + (u & 1);
        bias[u] = b_ih[R] + b_hh[R];
    }
    for (int k = u; k < HH; k += NTHR) wfc[k] = W_fc[k];

    const float bfc = b_fc[0];
    const bool  doy = (g == 0);
    const int   bA  = u & 63, bB2 = bA + 64;   // compute-tile batch rows
    const int   rp  = u >> 6;
    const int   rA  = rp << 1, rB = rA + 1;    // compute-tile gate rows
    const int   ub  = u & 127, ujj = u >> 7;   // update / y mapping
    const int   xb  = u >> 4, xq = u & 15;     // x float4 staging mapping
    const int   b2  = u & 127;                 // h staging: batch (coalesced)
    const int   kk0 = (u >> 7) << 5;           // h staging: 32-wide k range
    float creg = 0.f;
    float4 rx4[8];                             // x chunk (float4 path)
    float  rhA[32], rhB[32];                   // h chunk ping-pong buffers

#define LOAD_X(T) { _Pragma("unroll")                                             \
    for (int r8 = 0; r8 < 8; ++r8)                                                \
        rx4[r8] = *(const float4*)(x + ((size_t)(xb + 16*r8) * TT + (T)) * II     \
                                     + (xq << 2)); }

#define STAGE_X { _Pragma("unroll")                                               \
    for (int r8 = 0; r8 < 8; ++r8)                                                \
        *(float4*)&vx[xb + 16*r8][xq << 2] = rx4[r8]; }

    // h chunk N (1..8) covers h columns [(N-1)*64, N*64); lanes walk b2 -> coalesced
#define LOAD_H(R, N) { const float* hp_ = hsrc + ((size_t)(((N)-1) << 6) + kk0) * BB + b2; \
    _Pragma("unroll")                                                             \
    for (int i = 0; i < 32; ++i)                                                  \
        (R)[i] = __hip_atomic_load(hp_ + (size_t)i * BB, __ATOMIC_RELAXED,        \
                                   __HIP_MEMORY_SCOPE_AGENT); }

#define STAGE_H(R) { _Pragma("unroll")                                            \
    for (int j = 0; j < 8; ++j) {                                                 \
        float4 f_; f_.x=(R)[4*j]; f_.y=(R)[4*j+1]; f_.z=(R)[4*j+2]; f_.w=(R)[4*j+3]; \
        *(float4*)&vx[b2][kk0 + (j << 2)] = f_; } }

#define COMPUTE(CH) {                                                             \
    const float* wra_ = &Wl[rA][(CH) << 6];                                       \
    const float* wrb_ = &Wl[rB][(CH) << 6];                                       \
    const float* va_  = &vx[bA][0];                                               \
    const float* vb_  = &vx[bB2][0];                                              \
    _Pragma("unroll")                                                             \
    for (int k4 = 0; k4 < 16; ++k4) {                                             \
        const float4 wa = *(const float4*)(wra_ + (k4 << 2));                     \
        const float4 wb = *(const float4*)(wrb_ + (k4 << 2));                     \
        const float4 pa = *(const float4*)(va_ + (k4 << 2));                      \
        const float4 pb = *(const float4*)(vb_ + (k4 << 2));                      \
        a00 += wa.x*pa.x + wa.y*pa.y + wa.z*pa.z + wa.w*pa.w;                     \
        a01 += wa.x*pb.x + wa.y*pb.y + wa.z*pb.z + wa.w*pb.w;                     \
        a10 += wb.x*pa.x + wb.y*pa.y + wb.z*pa.z + wb.w*pa.w;                     \
        a11 += wb.x*pb.x + wb.y*pb.y + wb.z*pb.z + wb.w*pb.w; } }

#define YPART(CH) if (doy && t > 0) {                                             \
    const float* wf_ = &wfc[(((CH)-1) << 6) + (ujj << 5)];                        \
    const float* vv_ = &vx[ub][ujj << 5];                                         \
    _Pragma("unroll")                                                             \
    for (int k4 = 0; k4 < 8; ++k4) {                                              \
        const float4 f4 = *(const float4*)(wf_ + (k4 << 2));                      \
        const float4 v4 = *(const float4*)(vv_ + (k4 << 2));                      \
        yacc += f4.x*v4.x + f4.y*v4.y + f4.z*v4.z + f4.w*v4.w; } }

    LOAD_X(0);   // hbuf buffer0 + flags zeroed by stream-ordered memset

    for (int t = 0; t < TT; ++t) {
        const float* __restrict__ hsrc = hbuf + (size_t)(t & 1) * HH * BB;
        float*       __restrict__ hdst = hbuf + (size_t)((t + 1) & 1) * HH * BB;

        float a00 = 0.f, a01 = 0.f, a10 = 0.f, a11 = 0.f, yacc = 0.f;

        // ch0 (x)
        __syncthreads(); STAGE_X;        __syncthreads(); LOAD_H(rhA, 1); COMPUTE(0);
        // ch1..8 (h), ping-pong reg buffers; loads issue after vx-ready barrier
        __syncthreads(); STAGE_H(rhA);   __syncthreads(); LOAD_H(rhB, 2); COMPUTE(1); YPART(1);
        __syncthreads(); STAGE_H(rhB);   __syncthreads(); LOAD_H(rhA, 3); COMPUTE(2); YPART(2);
        __syncthreads(); STAGE_H(rhA);   __syncthreads(); LOAD_H(rhB, 4); COMPUTE(3); YPART(3);
        __syncthreads(); STAGE_H(rhB);   __syncthreads(); LOAD_H(rhA, 5); COMPUTE(4); YPART(4);
        __syncthreads(); STAGE_H(rhA);   __syncthreads(); LOAD_H(rhB, 6); COMPUTE(5); YPART(5);
        __syncthreads(); STAGE_H(rhB);   __syncthreads(); LOAD_H(rhA, 7); COMPUTE(6); YPART(6);
        __syncthreads(); STAGE_H(rhA);   __syncthreads(); LOAD_H(rhB, 8); COMPUTE(7); YPART(7);
        __syncthreads(); STAGE_H(rhB);   __syncthreads();                 COMPUTE(8); YPART(8);

        if (doy && t > 0) yl[ujj][ub] = yacc;
        gl[rA][bA]  = a00 + bias[rA];
        gl[rA][bB2] = a01 + bias[rA];
        gl[rB][bA]  = a10 + bias[rB];
        gl[rB][bB2] = a11 + bias[rB];
        __syncthreads();

        {   // c/h update: (128 b) x (2 jj); h store is write-through (agent)
            const float gi = gl[0 + ujj][ub];
            const float gf = gl[2 + ujj][ub];
            const float gg = gl[4 + ujj][ub];
            const float go = gl[6 + ujj][ub];
            const float si = 1.f / (1.f + expf(-gi));
            const float sf = 1.f / (1.f + expf(-gf));
            const float tg = tanhf(gg);
            const float so = 1.f / (1.f + expf(-go));
            const float c  = sf * creg + si * tg;
            creg = c;
            const float hval = so * tanhf(c);
            __hip_atomic_store(hdst + (size_t)(j0 + ujj) * BB + ub, hval,
                               __ATOMIC_RELAXED, __HIP_MEMORY_SCOPE_AGENT);
            if (doy && t > 0 && u < BB)
                out[(size_t)u * TT + (t - 1)] = yl[0][u] + yl[1][u] + bfc;
        }

        // ---- flag barrier: no fences, no RMWs ----
        __syncthreads();   // every wave drains vmcnt -> h stores at coherence pt
        if (u == 0)
            __hip_atomic_store(&flags[g], (u32)(t + 1),
                               __ATOMIC_RELAXED, __HIP_MEMORY_SCOPE_AGENT);
        if (t + 1 < TT) LOAD_X(t + 1);   // prefetch next x during the poll
        if (t + 1 < TT || doy) {
            const u32 want = (u32)(t + 1);
            while (__hip_atomic_load(&flags[u], __ATOMIC_RELAXED,
                                     __HIP_MEMORY_SCOPE_AGENT) < want)
                __builtin_amdgcn_s_sleep(1);
        }
        __syncthreads();
    }

    // ---- epilogue: y for the final h (block 0 only) ----
    if (doy) {
        const float* __restrict__ hsrc = hbuf + (size_t)(TT & 1) * HH * BB;
        float yacc = 0.f;
        #pragma unroll 1
        for (int n = 1; n <= 8; ++n) {
            __syncthreads();
            LOAD_H(rhA, n);
            STAGE_H(rhA);
            __syncthreads();
            const float* wf_ = &wfc[((n - 1) << 6) + (ujj << 5)];
            const float* vv_ = &vx[ub][ujj << 5];
            #pragma unroll
            for (int k4 = 0; k4 < 8; ++k4) {
                const float4 f4 = *(const float4*)(wf_ + (k4 << 2));
                const float4 v4 = *(const float4*)(vv_ + (k4 << 2));
                yacc += f4.x*v4.x + f4.y*v4.y + f4.z*v4.z + f4.w*v4.w;
            }
        }
        yl[ujj][ub] = yacc;
        __syncthreads();
        if (u < BB) out[(size_t)u * TT + (TT - 1)] = yl[0][u] + yl[1][u] + bfc;
    }
#undef LOAD_X
#undef STAGE_X
#undef LOAD_H
#undef STAGE_H
#undef COMPUTE
#undef YPART
}

extern "C" void kernel_launch(void* const* d_in, const int* in_sizes, int n_in,
                              void* d_out, int out_size, void* d_ws, size_t ws_size,
                              hipStream_t stream) {
    (void)in_sizes; (void)n_in; (void)out_size; (void)ws_size;
    const float* x    = (const float*)d_in[0];
    const float* W_ih = (const float*)d_in[1];
    const float* W_hh = (const float*)d_in[2];
    const float* b_ih = (const float*)d_in[3];
    const float* b_hh = (const float*)d_in[4];
    const float* W_fc = (const float*)d_in[5];
    const float* b_fc = (const float*)d_in[6];
    float* out = (float*)d_out;

    u32*   flags = (u32*)d_ws;                       // 256 words (4KB reserved)
    float* hbuf  = (float*)((char*)d_ws + 4096);     // 2*[HH][BB] = 512KB

    // zero flags + h buffer 0 (read at t=0) each call -> replay-deterministic
    hipMemsetAsync(d_ws, 0, 4096 + (size_t)HH * BB * sizeof(float), stream);

    void* args[] = {(void*)&x, (void*)&W_ih, (void*)&W_hh, (void*)&b_ih,
                    (void*)&b_hh, (void*)&W_fc, (void*)&b_fc, (void*)&out,
                    (void*)&hbuf, (void*)&flags};
    hipError_t e = hipLaunchCooperativeKernel((const void*)lstm_persist,
                                              dim3(NBLK), dim3(NTHR), args, 0, stream);
    if (e != hipSuccess) {
        hipLaunchKernelGGL(lstm_persist, dim3(NBLK), dim3(NTHR), 0, stream,
                           x, W_ih, W_hh, b_ih, b_hh, W_fc, b_fc, out, hbuf, flags);
    }
}